// Round 7
// baseline (1368.707 us; speedup 1.0000x reference)
//
#include <hip/hip_runtime.h>
#include <hip/hip_bf16.h>

// Attention-augmented LSTM encoder. B=2048, T=128, N=128, H=256.
// softmax shift-invariance -> attention time-invariant; w_h/w_c/b_attn dead.
//
// Round 7: latency hiding via co-resident independent blocks.
// 512 blocks x 256 thr = 2 blocks/CU (requires <=256 VGPR -> wx moved from
// registers into a swizzled LDS stage; remote h fragments staged once per
// block into LDS instead of 4x-redundant per-wave L3 reads).
// Block = 16-row rowgroup x 64 h-cols (4-way col split, fan-in 4).
// Wave keeps 16 hcols x 4 gates = 48 B-frags = 192 VGPRs; cell in-register.
// Exchange protocol (proven in r5/r6): relaxed sc0sc1 L3 loads/stores,
// per-wave u8 flags packed in one 16B line per rowgroup, no atomics/fences.

#define B_ 2048
#define T_ 128
#define N_ 128
#define H_ 256
#define MR_ 16    // rows per rowgroup
#define RGN_ 128  // rowgroups

typedef float f32x4 __attribute__((ext_vector_type(4)));
typedef short bf16x8 __attribute__((ext_vector_type(8)));
typedef unsigned short u16;
typedef unsigned int u32;
typedef u32 u32x4 __attribute__((ext_vector_type(4)));
typedef u16 u16x4 __attribute__((ext_vector_type(4)));

__device__ __forceinline__ u16 f2bf(float f) {
  unsigned int u = __float_as_uint(f);
  u += 0x7fffu + ((u >> 16) & 1u);   // RNE
  return (u16)(u >> 16);
}
__device__ __forceinline__ float sigm(float x) { return 1.f / (1.f + __expf(-x)); }
__device__ __forceinline__ float tanh_(float x) {
  float e = __expf(2.f * x);
  return 1.f - 2.f / (e + 1.f);
}

// device-coherent (L3) ops, relaxed (no cache-maintenance instructions)
__device__ __forceinline__ bf16x8 ld16_dev(const u16* p) {
  bf16x8 v;
  asm volatile("global_load_dwordx4 %0, %1, off sc0 sc1" : "=v"(v) : "v"(p));
  return v;
}
__device__ __forceinline__ void st8_dev(u16* p, u16x4 v) {
  asm volatile("global_store_dwordx2 %0, %1, off sc0 sc1" :: "v"(p), "v"(v) : "memory");
}
__device__ __forceinline__ void st1_dev(unsigned char* p, u32 v) {
  asm volatile("global_store_byte %0, %1, off sc0 sc1" :: "v"(p), "v"(v) : "memory");
}
__device__ __forceinline__ u32x4 ld_flags(const unsigned char* p) {
  u32x4 f;
  asm volatile("global_load_dwordx4 %0, %1, off sc0 sc1\n\ts_waitcnt vmcnt(0)"
               : "=v"(f) : "v"(p) : "memory");
  return f;
}

// ---------------------------------------------------------------- kernel 1
__global__ __launch_bounds__(128) void attn_wx_kernel(
    const float* __restrict__ x, const float* __restrict__ w_attn,
    float* __restrict__ out0) {
  const int b = blockIdx.x;
  const int n = threadIdx.x;
  const float* xb = x + (size_t)b * (T_ * N_);
  __shared__ float red[N_];
  float xv[T_];
  float p = 0.f;
#pragma unroll
  for (int t = 0; t < T_; ++t) {
    xv[t] = xb[t * N_ + n];
    p += xv[t] * w_attn[2 * H_ + t];
  }
  red[n] = p;
  __syncthreads();
  float m = red[0];
  for (int i = 1; i < N_; ++i) m = fmaxf(m, red[i]);
  float e = __expf(p - m);
  __syncthreads();
  red[n] = e;
  __syncthreads();
  float s = 0.f;
  for (int i = 0; i < N_; ++i) s += red[i];
  const float a = e / s;
  float* ob = out0 + (size_t)b * (T_ * N_);
#pragma unroll
  for (int t = 0; t < T_; ++t) ob[t * N_ + n] = a * xv[t];
}

// ------------------------------------------------------- weight prepack
// frag(g16=0..15, q=0..3, kc=0..11) at ((g16*4+q)*12+kc)*512; elem j of lane l
// = W[q*256+g16*16+(l&15)][kc*32+((l>>4)<<3)+j], W = [w_ih | w_hh], K=384.
__global__ __launch_bounds__(256) void prepack_kernel(
    const float* __restrict__ w_ih, const float* __restrict__ w_hh,
    u16* __restrict__ wpk) {
  const int idx = blockIdx.x * 256 + threadIdx.x;  // 393216
  const int j = idx & 7;
  const int l = (idx >> 3) & 63;
  const int rest = idx >> 9;
  const int kc = rest % 12;
  const int wq = rest / 12;
  const int q = wq & 3;
  const int g16 = wq >> 2;
  const int grow = q * H_ + g16 * 16 + (l & 15);
  const int k = kc * 32 + ((l >> 4) << 3) + j;
  const float v = (k < N_) ? w_ih[(size_t)grow * N_ + k]
                           : w_hh[(size_t)grow * H_ + (k - N_)];
  wpk[idx] = f2bf(v);
}

// ---------------------------------------------------------------- kernel 2
__global__ __launch_bounds__(256, 2) void lstm_kernel(
    const float* __restrict__ wx,      // out0 f32 [B][T][N]
    const u16* __restrict__ wpk,
    const float* __restrict__ b_ih, const float* __restrict__ b_hh,
    float* __restrict__ out1,          // f32 [B][T][H]
    u16* __restrict__ hx,              // [2][RGN][8 frag][512 u16]
    unsigned char* __restrict__ flags) { // [RGN][16 u8]
  // LDS: wx stage (16x128 f32, XOR-swizzled on 16B granules, ping-pong),
  //      own-h ping-pong, remote-fragment stage (consumer-frag layout).
  __shared__ float xstage[2][2048];    // 2 x 8KB
  __shared__ u16 hsh[2][MR_][72];      // own 64 h-cols (+8 pad)
  __shared__ u16 fstage[8][512];       // 8KB (own 2 slots unused)

  const int bid = blockIdx.x;
  const int rg = bid >> 2, cg = bid & 3;
  const int rb = rg * MR_;
  const int tid  = threadIdx.x;
  const int w    = tid >> 6;           // wave 0..3
  const int lane = tid & 63;
  const int l15  = lane & 15;
  const int koff = (lane >> 4) << 3;
  const int g16  = cg * 4 + w;
  const int hcol = cg * 64 + w * 16 + l15;

  // persistent weights: 48 frags = 192 VGPRs
  bf16x8 wfrag[4][12];
  {
    const u16* wp = wpk + (size_t)(g16 * 48) * 512 + (size_t)lane * 8;
#pragma unroll
    for (int q = 0; q < 4; ++q)
#pragma unroll
      for (int kc = 0; kc < 12; ++kc)
        wfrag[q][kc] = *(const bf16x8*)(wp + (size_t)(q * 12 + kc) * 512);
  }
  float bias[4];
#pragma unroll
  for (int q = 0; q < 4; ++q)
    bias[q] = b_ih[q * H_ + hcol] + b_hh[q * H_ + hcol];
  float creg[4] = {};

  unsigned char* flrow  = flags + rg * 16;
  unsigned char* myflag = flrow + cg * 4 + w;

  // wx staging geometry: dest byte d = w*2048 + i*1024 + lane*16 (linear);
  // row = d>>9, dest granule gd=(d>>4)&31, source granule = gd ^ (row&7).
  int srow[2], scol[2];
#pragma unroll
  for (int i = 0; i < 2; ++i) {
    const int d = w * 2048 + i * 1024 + lane * 16;
    srow[i] = d >> 9;
    scol[i] = ((((d >> 4) & 31) ^ (srow[i] & 7)) << 2);  // f32 index
  }
  // export geometry (loop-invariant)
  const int e0 = w * 256 + lane * 4;
  const int ef = e0 >> 9, er = e0 & 511;
  const int erow = (er >> 3) & 15;
  const int ecol = ((er >> 7) << 3) + (er & 7);

  // prologue: stage wx(t=0) into xstage[0]
  {
    f32x4 v0 = *(const f32x4*)(wx + (size_t)(rb + srow[0]) * (T_ * N_) + scol[0]);
    f32x4 v1 = *(const f32x4*)(wx + (size_t)(rb + srow[1]) * (T_ * N_) + scol[1]);
    *(f32x4*)((char*)&xstage[0][0] + w * 2048 + lane * 16) = v0;
    *(f32x4*)((char*)&xstage[0][0] + w * 2048 + 1024 + lane * 16) = v1;
  }
  __syncthreads();

  const int rmask = l15 & 7;

  for (int t = 0; t < T_; ++t) {
    const int par = t & 1, np = par ^ 1;

    f32x4 acc[4];
#pragma unroll
    for (int q = 0; q < 4; ++q)
      acc[q] = (f32x4){bias[q], bias[q], bias[q], bias[q]};

    // ---- A) wx MFMAs from swizzled LDS (independent of the exchange)
#pragma unroll
    for (int kc = 0; kc < 4; ++kc) {
      const int g = kc * 8 + (koff >> 2);   // source granule (even)
      const char* bp = (const char*)&xstage[par][0] + l15 * 512;
      f32x4 x0 = *(const f32x4*)(bp + ((g ^ rmask) << 4));
      f32x4 x1 = *(const f32x4*)(bp + (((g + 1) ^ rmask) << 4));
      bf16x8 a;
      a[0] = (short)f2bf(x0[0]); a[1] = (short)f2bf(x0[1]);
      a[2] = (short)f2bf(x0[2]); a[3] = (short)f2bf(x0[3]);
      a[4] = (short)f2bf(x1[0]); a[5] = (short)f2bf(x1[1]);
      a[6] = (short)f2bf(x1[2]); a[7] = (short)f2bf(x1[3]);
#pragma unroll
      for (int q = 0; q < 4; ++q)
        acc[q] = __builtin_amdgcn_mfma_f32_16x16x32_bf16(a, wfrag[q][kc], acc[q], 0, 0, 0);
    }

    // ---- issue wx loads for t+1 (latency overlaps poll + h-MFMA)
    f32x4 wv0, wv1;
    const bool dowx = (t + 1 < T_);
    if (dowx) {
      const float* p0 = wx + (size_t)(rb + srow[0]) * (T_ * N_) + (size_t)(t + 1) * N_ + scol[0];
      const float* p1 = wx + (size_t)(rb + srow[1]) * (T_ * N_) + (size_t)(t + 1) * N_ + scol[1];
      wv0 = *(const f32x4*)p0;
      wv1 = *(const f32x4*)p1;
    }

    // ---- B/C) poll + stage remote fragments into LDS (once per block)
    if (t > 0) {
      while (true) {
        u32x4 f = ld_flags(flrow);
        int ok = 1;
#pragma unroll
        for (int i = 0; i < 4; ++i) {
          u32 v = f[i];
          ok &= ((v & 255u) >= (u32)t) & (((v >> 8) & 255u) >= (u32)t) &
                (((v >> 16) & 255u) >= (u32)t) & (((v >> 24) & 255u) >= (u32)t);
        }
        if (ok) break;
      }
      __builtin_amdgcn_sched_barrier(0);

      const u16* hxr = hx + ((size_t)par * RGN_ + rg) * 4096;
      bf16x8 fv0, fv1;
      int k0 = 0, k1 = 0;
      if (w < 3) {
        const int r0 = w * 2, r1 = w * 2 + 1;
        k0 = (r0 < 2 * cg) ? r0 : r0 + 2;
        k1 = (r1 < 2 * cg) ? r1 : r1 + 2;
        fv0 = ld16_dev(hxr + k0 * 512 + lane * 8);
        fv1 = ld16_dev(hxr + k1 * 512 + lane * 8);
      }
      asm volatile("s_waitcnt vmcnt(0)" ::: "memory");
      if (w < 3) {
        *(bf16x8*)&fstage[k0][lane * 8] = fv0;
        *(bf16x8*)&fstage[k1][lane * 8] = fv1;
      }
    }
    // commit wx(t+1) into the other xstage buffer (linear dest)
    if (dowx) {
      *(f32x4*)((char*)&xstage[np][0] + w * 2048 + lane * 16) = wv0;
      *(f32x4*)((char*)&xstage[np][0] + w * 2048 + 1024 + lane * 16) = wv1;
    }

    // ---- D/E) barrier, then h MFMAs (own cols from hsh, rest from fstage)
    if (t > 0) {
      __syncthreads();
#pragma unroll
      for (int kc2 = 0; kc2 < 8; ++kc2) {
        bf16x8 a;
        if ((kc2 >> 1) == cg)   // block-uniform branch
          a = *(const bf16x8*)&hsh[par][l15][(kc2 & 1) * 32 + koff];
        else
          a = *(const bf16x8*)&fstage[kc2][lane * 8];
#pragma unroll
        for (int q = 0; q < 4; ++q)
          acc[q] = __builtin_amdgcn_mfma_f32_16x16x32_bf16(a, wfrag[q][4 + kc2], acc[q], 0, 0, 0);
      }
    }

    // ---- F) LSTM cell (in-register; lane owns hcol in all 4 gate quadrants)
#pragma unroll
    for (int rr = 0; rr < 4; ++rr) {
      const float gi = acc[0][rr];
      const float gf = acc[1][rr];
      const float gg = acc[2][rr];
      const float go = acc[3][rr];
      const float c = sigm(gf) * creg[rr] + sigm(gi) * tanh_(gg);
      creg[rr] = c;
      const float h = sigm(go) * tanh_(c);
      const int row = ((lane >> 4) << 2) + rr;
      out1[(size_t)(rb + row) * (T_ * H_) + (size_t)t * H_ + hcol] = h;
      hsh[np][row][w * 16 + l15] = f2bf(h);
    }
    __syncthreads();   // hsh[np] + xstage[np] complete across all waves

    // ---- G) export own tile as consumer-ready fragments + flag
    {
      u16x4 v = *(const u16x4*)&hsh[np][erow][ef * 32 + ecol];
      u16* dst = hx + ((size_t)np * RGN_ + rg) * 4096 + cg * 1024 + e0;
      st8_dev(dst, v);
      asm volatile("s_waitcnt vmcnt(0)" ::: "memory");  // data at L3
      if (lane == 0) st1_dev(myflag, (u32)(t + 1));
    }
  }
}

// ---------------------------------------------------------------- launch
extern "C" void kernel_launch(void* const* d_in, const int* in_sizes, int n_in,
                              void* d_out, int out_size, void* d_ws, size_t ws_size,
                              hipStream_t stream) {
  const float* x      = (const float*)d_in[0];
  const float* w_ih   = (const float*)d_in[1];
  const float* w_hh   = (const float*)d_in[2];
  const float* b_ih   = (const float*)d_in[3];
  const float* b_hh   = (const float*)d_in[4];
  const float* w_attn = (const float*)d_in[5];
  // d_in[6] (b_attn) provably unused (softmax shift invariance).

  float* out0 = (float*)d_out;                   // [B][T][N] input_weighted
  float* out1 = out0 + (size_t)B_ * T_ * N_;     // [B][T][H] input_encoded

  unsigned char* flags = (unsigned char*)d_ws;               // 2 KB
  u16* wpk = (u16*)((char*)d_ws + 16384);                    // 768 KB
  u16* hx  = (u16*)((char*)d_ws + 16384 + 786432);           // 2 MB

  hipMemsetAsync(d_ws, 0, RGN_ * 16, stream);
  prepack_kernel<<<dim3(1536), dim3(256), 0, stream>>>(w_ih, w_hh, wpk);
  attn_wx_kernel<<<dim3(B_), dim3(N_), 0, stream>>>(x, w_attn, out0);
  lstm_kernel<<<dim3(RGN_ * 4), dim3(256), 0, stream>>>(out0, wpk, b_ih, b_hh,
                                                        out1, hx, flags);
}

// Round 9
// 829.378 us; speedup vs baseline: 1.6503x; 1.6503x over previous
//
#include <hip/hip_runtime.h>
#include <hip/hip_bf16.h>

// Attention-augmented LSTM encoder. B=2048, T=128, N=128, H=256.
// softmax shift-invariance -> attention time-invariant; w_h/w_c/b_attn dead.
//
// Round 9 = round 6 (best proven: 961us) + two SAFE chain fixes (the r8
// XCD-colo path deadlocked on a wrong runtime XCC check -- removed):
//  1) loop rotated: poll first (nothing of ours outstanding); wx prefetch
//     and partner loads share ONE vmcnt(0); next-step wx MFMA at loop end
//     (producer slack, overlaps consumers' polls).
//  2) out1 moved off the exchange chain: h staged in LDS (f32); export
//     fragment issued FIRST, then out1 stores, then vmcnt(2) -- waits only
//     for the oldest op (the export; vmcnt retires oldest-first, m135) --
//     then the flag byte. out1 acks drain inside the NEXT poll, overlapped
//     with the producer wait.
// Exchange protocol unchanged from r5/r6 (proven): relaxed sc0sc1 L3
// loads/stores, 16 u8 flags in one 16B line per rowgroup (padded to 128B),
// no atomics, no acquire/release fences.

#define B_ 2048
#define T_ 128
#define N_ 128
#define H_ 256
#define RG_ 64   // rowgroups of 32 rows

typedef float f32x4 __attribute__((ext_vector_type(4)));
typedef short bf16x8 __attribute__((ext_vector_type(8)));
typedef unsigned short u16;
typedef unsigned int u32;
typedef u32 u32x4 __attribute__((ext_vector_type(4)));

__device__ __forceinline__ u16 f2bf(float f) {
  unsigned int u = __float_as_uint(f);
  u += 0x7fffu + ((u >> 16) & 1u);   // RNE
  return (u16)(u >> 16);
}
__device__ __forceinline__ float sigm(float x) { return 1.f / (1.f + __expf(-x)); }
__device__ __forceinline__ float tanh_(float x) {
  float e = __expf(2.f * x);
  return 1.f - 2.f / (e + 1.f);
}

// device-coherent (L3) ops, relaxed (no cache-maintenance instructions)
__device__ __forceinline__ bf16x8 ld16_dev(const u16* p) {
  bf16x8 v;
  asm volatile("global_load_dwordx4 %0, %1, off sc0 sc1" : "=v"(v) : "v"(p));
  return v;
}
__device__ __forceinline__ void st16_dev(u16* p, bf16x8 v) {
  asm volatile("global_store_dwordx4 %0, %1, off sc0 sc1" :: "v"(p), "v"(v) : "memory");
}
__device__ __forceinline__ void st1_dev(unsigned char* p, u32 v) {
  asm volatile("global_store_byte %0, %1, off sc0 sc1" :: "v"(p), "v"(v) : "memory");
}
__device__ __forceinline__ u32x4 ld_flags(const unsigned char* p) {
  u32x4 f;
  asm volatile("global_load_dwordx4 %0, %1, off sc0 sc1\n\ts_waitcnt vmcnt(0)"
               : "=v"(f) : "v"(p) : "memory");
  return f;
}

// ---------------------------------------------------------------- kernel 1
__global__ __launch_bounds__(128) void attn_wx_kernel(
    const float* __restrict__ x, const float* __restrict__ w_attn,
    float* __restrict__ out0) {
  const int b = blockIdx.x;
  const int n = threadIdx.x;
  const float* xb = x + (size_t)b * (T_ * N_);
  __shared__ float red[N_];
  float xv[T_];
  float p = 0.f;
#pragma unroll
  for (int t = 0; t < T_; ++t) {
    xv[t] = xb[t * N_ + n];
    p += xv[t] * w_attn[2 * H_ + t];
  }
  red[n] = p;
  __syncthreads();
  float m = red[0];
  for (int i = 1; i < N_; ++i) m = fmaxf(m, red[i]);
  float e = __expf(p - m);
  __syncthreads();
  red[n] = e;
  __syncthreads();
  float s = 0.f;
  for (int i = 0; i < N_; ++i) s += red[i];
  const float a = e / s;
  float* ob = out0 + (size_t)b * (T_ * N_);
#pragma unroll
  for (int t = 0; t < T_; ++t) ob[t * N_ + n] = a * xv[t];
}

// ------------------------------------------------------- weight prepack
// frag(g16=0..15, q=0..3, kc=0..11) at ((g16*4+q)*12+kc)*512; elem j of lane l
// = W[q*256+g16*16+(l&15)][kc*32+((l>>4)<<3)+j], W = [w_ih | w_hh], K=384.
__global__ __launch_bounds__(256) void prepack_kernel(
    const float* __restrict__ w_ih, const float* __restrict__ w_hh,
    u16* __restrict__ wpk) {
  const int idx = blockIdx.x * 256 + threadIdx.x;  // 393216
  const int j = idx & 7;
  const int l = (idx >> 3) & 63;
  const int rest = idx >> 9;
  const int kc = rest % 12;
  const int wq = rest / 12;
  const int q = wq & 3;
  const int g16 = wq >> 2;
  const int grow = q * H_ + g16 * 16 + (l & 15);
  const int k = kc * 32 + ((l >> 4) << 3) + j;
  const float v = (k < N_) ? w_ih[(size_t)grow * N_ + k]
                           : w_hh[(size_t)grow * H_ + (k - N_)];
  wpk[idx] = f2bf(v);
}

// ---------------------------------------------------------------- kernel 2
__global__ __launch_bounds__(256, 1) void lstm_kernel(
    const float* __restrict__ wx,      // out0 f32 [B][T][N]
    const u16* __restrict__ wpk,
    const float* __restrict__ b_ih, const float* __restrict__ b_hh,
    float* __restrict__ out1,          // f32 [B][T][H]
    u16* __restrict__ hx,              // [2][RG][16 frag][512 u16]
    unsigned char* __restrict__ flags) { // [RG][128B line; 16 u8 used]
  __shared__ u16 hsh[2][32][72];       // own 64 h-cols (bf16), ping-pong
  __shared__ float osh[2][32][68];     // h f32 staging for coalesced out1
  const int bid = blockIdx.x;
  const int rg = bid >> 2, cg = bid & 3;
  const int rb = rg * 32;
  const int tid  = threadIdx.x;
  const int w    = tid >> 6;           // wave 0..3
  const int lane = tid & 63;
  const int l15  = lane & 15;
  const int koff = (lane >> 4) << 3;
  const int g16  = cg * 4 + w;
  const int hcol = cg * 64 + w * 16 + l15;

  // persistent weights: 48 frags = 192 VGPRs
  bf16x8 wfrag[4][12];
  {
    const u16* wp = wpk + (size_t)(g16 * 48) * 512 + (size_t)lane * 8;
#pragma unroll
    for (int q = 0; q < 4; ++q)
#pragma unroll
      for (int kc = 0; kc < 12; ++kc)
        wfrag[q][kc] = *(const bf16x8*)(wp + (size_t)(q * 12 + kc) * 512);
  }
  float bias[4];
#pragma unroll
  for (int q = 0; q < 4; ++q)
    bias[q] = b_ih[q * H_ + hcol] + b_hh[q * H_ + hcol];
  float creg[2][4] = {};

  unsigned char* flrow  = flags + (size_t)rg * 128;
  unsigned char* myflag = flrow + cg * 4 + w;
  const int mtf = w >> 1, kclf = w & 1;   // fragment this wave exports

  // ---- prologue: wx(0) -> pf; acc = bias + wx-part(0)
  f32x4 pf[2][4][2];
  f32x4 acc[2][4];
#pragma unroll
  for (int mt = 0; mt < 2; ++mt)
#pragma unroll
    for (int kc = 0; kc < 4; ++kc) {
      const float* p = wx + (size_t)(rb + mt * 16 + l15) * (T_ * N_) + kc * 32 + koff;
      pf[mt][kc][0] = *(const f32x4*)p;
      pf[mt][kc][1] = *(const f32x4*)(p + 4);
    }
#pragma unroll
  for (int mt = 0; mt < 2; ++mt)
#pragma unroll
    for (int q = 0; q < 4; ++q)
      acc[mt][q] = (f32x4){bias[q], bias[q], bias[q], bias[q]};
#pragma unroll
  for (int kc = 0; kc < 4; ++kc)
#pragma unroll
    for (int mt = 0; mt < 2; ++mt) {
      f32x4 x0 = pf[mt][kc][0], x1 = pf[mt][kc][1];
      bf16x8 a;
      a[0] = (short)f2bf(x0[0]); a[1] = (short)f2bf(x0[1]);
      a[2] = (short)f2bf(x0[2]); a[3] = (short)f2bf(x0[3]);
      a[4] = (short)f2bf(x1[0]); a[5] = (short)f2bf(x1[1]);
      a[6] = (short)f2bf(x1[2]); a[7] = (short)f2bf(x1[3]);
#pragma unroll
      for (int q = 0; q < 4; ++q)
        acc[mt][q] = __builtin_amdgcn_mfma_f32_16x16x32_bf16(a, wfrag[q][kc], acc[mt][q], 0, 0, 0);
    }

  for (int t = 0; t < T_; ++t) {
    const int par = t & 1, np = par ^ 1;

    // ---- A) poll (only last step's 2 out1 stores + flag byte outstanding;
    //          their drain overlaps the wait for producers)
    if (t > 0) {
      while (true) {
        u32x4 f = ld_flags(flrow);
        int ok = 1;
#pragma unroll
        for (int i = 0; i < 4; ++i) {
          u32 v = f[i];
          ok &= ((v & 255u) >= (u32)t) & (((v >> 8) & 255u) >= (u32)t) &
                (((v >> 16) & 255u) >= (u32)t) & (((v >> 24) & 255u) >= (u32)t);
        }
        if (ok) break;
      }
      __builtin_amdgcn_sched_barrier(0);
    }

    // ---- B) issue wx prefetch(t+1) + partner fragment loads; ONE drain.
    const bool dowx = (t + 1 < T_);
    if (dowx) {
#pragma unroll
      for (int mt = 0; mt < 2; ++mt)
#pragma unroll
        for (int kc = 0; kc < 4; ++kc) {
          const float* p = wx + (size_t)(rb + mt * 16 + l15) * (T_ * N_)
                              + (size_t)(t + 1) * N_ + kc * 32 + koff;
          pf[mt][kc][0] = *(const f32x4*)p;
          pf[mt][kc][1] = *(const f32x4*)(p + 4);
        }
    }
    if (t > 0) {
      const u16* hxr = hx + ((size_t)par * RG_ + rg) * 8192;
      bf16x8 ah[2][8];
#pragma unroll
      for (int mt = 0; mt < 2; ++mt)
#pragma unroll
        for (int kc2 = 0; kc2 < 8; ++kc2) {
          const int pc = kc2 >> 1, kcl = kc2 & 1;
          if (pc == cg)   // block-uniform branch
            ah[mt][kc2] = *(const bf16x8*)&hsh[par][mt * 16 + l15][kcl * 32 + koff];
          else
            ah[mt][kc2] = ld16_dev(hxr + ((size_t)pc * 4 + (mt * 2 + kcl)) * 512
                                       + (size_t)lane * 8);
        }
      asm volatile("s_waitcnt vmcnt(0)" ::: "memory");   // partner + pf
      __builtin_amdgcn_sched_barrier(0);
#pragma unroll
      for (int kc2 = 0; kc2 < 8; ++kc2)
#pragma unroll
        for (int q = 0; q < 4; ++q)
#pragma unroll
          for (int mt = 0; mt < 2; ++mt)
            acc[mt][q] = __builtin_amdgcn_mfma_f32_16x16x32_bf16(ah[mt][kc2], wfrag[q][4 + kc2], acc[mt][q], 0, 0, 0);
    } else {
      asm volatile("s_waitcnt vmcnt(0)" ::: "memory");   // pf only (t==0)
    }

    // ---- C) LSTM cell -> hsh[np] (bf16) + osh[par] (f32)
#pragma unroll
    for (int mt = 0; mt < 2; ++mt)
#pragma unroll
      for (int rr = 0; rr < 4; ++rr) {
        const float gi = acc[mt][0][rr];
        const float gf = acc[mt][1][rr];
        const float gg = acc[mt][2][rr];
        const float go = acc[mt][3][rr];
        const float c = sigm(gf) * creg[mt][rr] + sigm(gi) * tanh_(gg);
        creg[mt][rr] = c;
        const float h = sigm(go) * tanh_(c);
        const int row = mt * 16 + ((lane >> 4) << 2) + rr;
        osh[par][row][w * 16 + l15] = h;
        hsh[np][row][w * 16 + l15] = f2bf(h);
      }
    __syncthreads();

    // ---- D) export fragment FIRST, then out1; wait only for the export
    //          (oldest of 3 outstanding -> vmcnt(2)); then publish flag.
    {
      bf16x8 fv = *(const bf16x8*)&hsh[np][mtf * 16 + l15][kclf * 32 + koff];
      u16* dst = hx + ((size_t)np * RG_ + rg) * 8192 + (size_t)(cg * 4 + w) * 512
                    + (size_t)lane * 8;
      st16_dev(dst, fv);
    }
#pragma unroll
    for (int i = 0; i < 2; ++i) {
      const int row = w * 8 + (lane >> 4) + i * 4;
      float* op = out1 + (size_t)(rb + row) * (T_ * H_) + (size_t)t * H_
                       + cg * 64 + l15 * 4;
      *(f32x4*)op = *(const f32x4*)&osh[par][row][l15 * 4];
    }
    asm volatile("s_waitcnt vmcnt(2)" ::: "memory");   // export done; out1 in flight
    if (lane == 0) st1_dev(myflag, (u32)(t + 1));

    // ---- E) wx-part MFMAs for t+1 (producer slack; overlaps partner polls)
    if (dowx) {
#pragma unroll
      for (int mt = 0; mt < 2; ++mt)
#pragma unroll
        for (int q = 0; q < 4; ++q)
          acc[mt][q] = (f32x4){bias[q], bias[q], bias[q], bias[q]};
#pragma unroll
      for (int kc = 0; kc < 4; ++kc)
#pragma unroll
        for (int mt = 0; mt < 2; ++mt) {
          f32x4 x0 = pf[mt][kc][0], x1 = pf[mt][kc][1];
          bf16x8 a;
          a[0] = (short)f2bf(x0[0]); a[1] = (short)f2bf(x0[1]);
          a[2] = (short)f2bf(x0[2]); a[3] = (short)f2bf(x0[3]);
          a[4] = (short)f2bf(x1[0]); a[5] = (short)f2bf(x1[1]);
          a[6] = (short)f2bf(x1[2]); a[7] = (short)f2bf(x1[3]);
#pragma unroll
          for (int q = 0; q < 4; ++q)
            acc[mt][q] = __builtin_amdgcn_mfma_f32_16x16x32_bf16(a, wfrag[q][kc], acc[mt][q], 0, 0, 0);
        }
    }
  }
}

// ---------------------------------------------------------------- launch
extern "C" void kernel_launch(void* const* d_in, const int* in_sizes, int n_in,
                              void* d_out, int out_size, void* d_ws, size_t ws_size,
                              hipStream_t stream) {
  const float* x      = (const float*)d_in[0];
  const float* w_ih   = (const float*)d_in[1];
  const float* w_hh   = (const float*)d_in[2];
  const float* b_ih   = (const float*)d_in[3];
  const float* b_hh   = (const float*)d_in[4];
  const float* w_attn = (const float*)d_in[5];
  // d_in[6] (b_attn) provably unused (softmax shift invariance).

  float* out0 = (float*)d_out;                   // [B][T][N] input_weighted
  float* out1 = out0 + (size_t)B_ * T_ * N_;     // [B][T][H] input_encoded

  unsigned char* flags = (unsigned char*)d_ws;               // 8 KB (64x128B)
  u16* wpk  = (u16*)((char*)d_ws + 16384);                   // 768 KB
  u16* hx   = (u16*)((char*)d_ws + 16384 + 786432);          // 2 MB

  hipMemsetAsync(flags, 0, 8192, stream);
  prepack_kernel<<<dim3(1536), dim3(256), 0, stream>>>(w_ih, w_hh, wpk);
  attn_wx_kernel<<<dim3(B_), dim3(N_), 0, stream>>>(x, w_attn, out0);
  lstm_kernel<<<dim3(256), dim3(256), 0, stream>>>(out0, wpk, b_ih, b_hh,
                                                   out1, hx, flags);
}